// Round 4
// baseline (17140.489 us; speedup 1.0000x reference)
//
#include <hip/hip_runtime.h>

// DecoderGRU: 2-layer GRU (B=64, H=1024, T=1024, OUT=128) + output projection.
// R13 = TWO-PASS SELF-TIMING ABLATION (correct output; dur = T_real + T_floor).
// R12 lesson: harness gives no timing/profile on failed correctness. So the
// ablation runs as PASS A inside a passing kernel: pollers release
// immediately (no cross-block waits), data path byte-identical in structure,
// loads in bypass mode (sc0 sc1) so no garbage lines enter L2. PASS B
// re-inits state (hm, h^-1 slot 23, sync vars, real flags after l2inv) and
// runs the exact R11 protocol -> correct output. Known T_real ~11.5ms =>
// floor = dur - 11.5ms.
// Pre-committed: dur~21-23ms -> data path dominates; 13.5-15.5ms -> sync
// chain dominates; middle -> both. FETCH/WRITE ~2x confirms pass-A traffic.
// Safety: every pass-B read gated by pass-B flags (set only after producer
// finished pass A, program order); pass-A writes touch only own slices,
// re-inited/rewritten before gated reads; out garbage overwritten by same
// threads in pass B; pass-A flag writes go to scratch flag region.
//   S0 (blk 0-63):   h0^t = GRU0(h0^{t-1})        [16 units/blk]
//   S1 (blk 64-127): Gx^t = y0^t @ W_ih1^T        [16 units/blk]
//   S2 (blk 128-191): h1^t = GRU1(Gx^t, h1^{t-1}) [16 units/blk]
//   S3 (blk 192-199): out^t = y1^t @ W_out^T + b  [16 cols/blk]

#define NBLK 200
#define SMEM_BYTES 152576
#define H 1024
#define T 1024
#define NSLOT 24
#define SLOT(k) (((k) + NSLOT) % NSLOT)
#define MEMBAR asm volatile("" ::: "memory")

typedef short s16x8 __attribute__((ext_vector_type(8)));
typedef float f32x4 __attribute__((ext_vector_type(4)));

__device__ __forceinline__ unsigned short f2bf(float f) {
  union { float f; unsigned u; } v; v.f = f;
  return (unsigned short)((v.u + 0x7FFFu + ((v.u >> 16) & 1u)) >> 16);
}
__device__ __forceinline__ float sigm(float x) { return 1.f / (1.f + __expf(-x)); }

__device__ __forceinline__ void st_u16(void* p, unsigned short v) {
  __hip_atomic_store((unsigned short*)p, v, __ATOMIC_RELAXED, __HIP_MEMORY_SCOPE_AGENT);
}
__device__ __forceinline__ void st_i32(int* p, int v) {
  __hip_atomic_store(p, v, __ATOMIC_RELAXED, __HIP_MEMORY_SCOPE_AGENT);
}
__device__ __forceinline__ int ld_i32(const int* p) {
  return __hip_atomic_load(p, __ATOMIC_RELAXED, __HIP_MEMORY_SCOPE_AGENT);
}

__device__ __forceinline__ void l2inv() {
  __builtin_amdgcn_fence(__ATOMIC_ACQUIRE, "agent");
}

// Cached (sc0: L1-bypass, L2-cached) and Bypass (sc0 sc1) load flavors.
#define GLDC(d, p, off) \
  asm volatile("global_load_dwordx4 %0, %1, off offset:" #off " sc0" \
               : "=v"(d) : "v"(p))
#define GLDB(d, p, off) \
  asm volatile("global_load_dwordx4 %0, %1, off offset:" #off " sc0 sc1" \
               : "=v"(d) : "v"(p))
#define WAITV(n) asm volatile("s_waitcnt vmcnt(" #n ")" ::: "memory")
#define TIE4(A) \
  asm volatile("" : "+v"(A[0]),"+v"(A[1]),"+v"(A[2]),"+v"(A[3]))

template<bool BYP>
__device__ __forceinline__ void gldg(s16x8 (&A)[4], const unsigned short* p) {
  if (BYP) { GLDB(A[0],p,0); GLDB(A[1],p,64); GLDB(A[2],p,128); GLDB(A[3],p,192); }
  else     { GLDC(A[0],p,0); GLDC(A[1],p,64); GLDC(A[2],p,128); GLDC(A[3],p,192); }
}

// ---- coherent (L2-bypass) stores + gx loads: unchanged publish protocol --
__device__ __forceinline__ void gst16f(f32x4 v, void* p) {
  asm volatile("global_store_dwordx4 %0, %1, off sc0 sc1" :: "v"(p), "v"(v) : "memory");
}
__device__ __forceinline__ void gst4(float v, void* p) {
  asm volatile("global_store_dword %0, %1, off sc0 sc1" :: "v"(p), "v"(v) : "memory");
}
__device__ __forceinline__ void gst4u(unsigned v, void* p) {
  asm volatile("global_store_dword %0, %1, off sc0 sc1" :: "v"(p), "v"(v) : "memory");
}
__device__ __forceinline__ f32x4 gldf(const float* p) {
  f32x4 d;
  asm volatile("global_load_dwordx4 %0, %1, off sc0 sc1" : "=v"(d) : "v"(p));
  return d;
}

// Wave-7 poller, 2-deep pipelined (identical to R9-R11). Real pass only.
__device__ __forceinline__ void poller(const int* fd, int dtgt,
                                       const int* fgx, int gtgt,
                                       const int* fa, int na, int atgt,
                                       volatile int* ready, int t, int lane) {
  {
    const int* fp = fd + lane;
    int v = ld_i32(fp);
    for (;;) {
      int vn = ld_i32(fp);
      unsigned long long m = __ballot(v >= dtgt);
      if (lane < 8 && ((m >> (8 * lane)) & 0xFFull) == 0xFFull) ready[lane] = t;
      if (m == ~0ull) break;
      v = vn;
    }
  }
  if (fgx) {
    int v = (lane == 0) ? ld_i32(fgx) : 0x7fffffff;
    for (;;) {
      int vn = (lane == 0) ? ld_i32(fgx) : 0x7fffffff;
      if (__ballot(v < gtgt) == 0ull) break;
      v = vn;
    }
    if (lane == 0) ready[8] = t;
  }
  if (fa) {
    bool act = lane < na;
    const int* fp = fa + (act ? lane : 0);
    int v = act ? ld_i32(fp) : atgt;
    for (;;) {
      int vn = act ? ld_i32(fp) : atgt;
      if (__ballot(v < atgt) == 0ull) break;
      v = vn;
    }
  }
}

#define MF3(Ap, g) { \
  _Pragma("unroll") \
  for (int i = 0; i < 4; ++i) { int kb = (g)*4 + i; \
    s16x8 b0 = *(const s16x8*)(bb + (kb*3+0)*512); \
    s16x8 b1 = *(const s16x8*)(bb + (kb*3+1)*512); \
    s16x8 b2 = *(const s16x8*)(bb + (kb*3+2)*512); \
    a0 = __builtin_amdgcn_mfma_f32_16x16x32_bf16(Ap[i], b0, a0, 0, 0, 0); \
    a1 = __builtin_amdgcn_mfma_f32_16x16x32_bf16(Ap[i], b1, a1, 0, 0, 0); \
    a2 = __builtin_amdgcn_mfma_f32_16x16x32_bf16(Ap[i], b2, a2, 0, 0, 0); } }

#define MF1(Ap, g) { \
  _Pragma("unroll") \
  for (int i = 0; i < 4; ++i) { int kb = (g)*4 + i; \
    s16x8 b0 = *(const s16x8*)(bb + kb*512); \
    a0 = __builtin_amdgcn_mfma_f32_16x16x32_bf16(Ap[i], b0, a0, 0, 0, 0); } }

// N=48 GEMM, group-pipelined (identical compute to R11).
template<bool BYP>
__device__ __forceinline__ void gemm48(const unsigned short* arow,
                                       const unsigned short* bb,
                                       volatile int* ready, int t,
                                       float* G, int ldg, int lane, int w) {
  f32x4 a0 = {0,0,0,0}, a1 = {0,0,0,0}, a2 = {0,0,0,0};
  s16x8 A0[4], A1[4];
  while (ready[0] < t) {}
  MEMBAR;
  gldg<BYP>(A0, arow);
  while (ready[1] < t) {}
  MEMBAR;
  gldg<BYP>(A1, arow + 128);
  #pragma unroll
  for (int g2 = 1; g2 < 4; ++g2) {
    WAITV(4); TIE4(A0); MF3(A0, 2*g2 - 2);
    while (ready[2*g2] < t) {}
    MEMBAR;
    gldg<BYP>(A0, arow + g2*256);
    WAITV(4); TIE4(A1); MF3(A1, 2*g2 - 1);
    while (ready[2*g2 + 1] < t) {}
    MEMBAR;
    gldg<BYP>(A1, arow + g2*256 + 128);
  }
  WAITV(4); TIE4(A0); MF3(A0, 6);
  WAITV(0); TIE4(A1); MF3(A1, 7);
  int col = lane & 15, r0 = (lane >> 4) * 4;
  #pragma unroll
  for (int r = 0; r < 4; ++r) {
    int brow = w*16 + r0 + r;
    G[brow*ldg +      col] = a0[r];
    G[brow*ldg + 16 + col] = a1[r];
    G[brow*ldg + 32 + col] = a2[r];
  }
}

// S3 GEMM step (N=16), identical compute to R11's inline body.
template<bool BYP>
__device__ __forceinline__ void s3_gemm(const unsigned short* arow,
                                        const unsigned short* bb,
                                        volatile int* ready, int t,
                                        const float* bo, float* out,
                                        int base, int lane, int w) {
  f32x4 a0 = {0,0,0,0};
  s16x8 A0[4], A1[4];
  while (ready[0] < t) {}
  MEMBAR;
  gldg<BYP>(A0, arow);
  while (ready[1] < t) {}
  MEMBAR;
  gldg<BYP>(A1, arow + 128);
  #pragma unroll
  for (int g2i = 1; g2i < 4; ++g2i) {
    WAITV(4); TIE4(A0); MF1(A0, 2*g2i - 2);
    while (ready[2*g2i] < t) {}
    MEMBAR;
    gldg<BYP>(A0, arow + g2i*256);
    WAITV(4); TIE4(A1); MF1(A1, 2*g2i - 1);
    while (ready[2*g2i + 1] < t) {}
    MEMBAR;
    gldg<BYP>(A1, arow + g2i*256 + 128);
  }
  WAITV(4); TIE4(A0); MF1(A0, 6);
  WAITV(0); TIE4(A1); MF1(A1, 7);
  int col = lane & 15, r0 = (lane >> 4) * 4;
  #pragma unroll
  for (int r = 0; r < 4; ++r) {
    int brow = w*16 + r0 + r;
    gst4(a0[r] + bo[col], out + (size_t)(brow*T + t)*128 + base + col);
  }
}

extern "C" __global__ void __launch_bounds__(512, 1)
gru_pipeline(const float* __restrict__ z,
             const float* __restrict__ Whh0,
             const float* __restrict__ bih0, const float* __restrict__ bhh0,
             const float* __restrict__ Wih1, const float* __restrict__ Whh1,
             const float* __restrict__ bih1, const float* __restrict__ bhh1,
             const float* __restrict__ Wout, const float* __restrict__ bout,
             float* __restrict__ out, char* __restrict__ ws)
{
  extern __shared__ char smem[];
  const int tid  = threadIdx.x;
  const int lane = tid & 63;
  const int w    = tid >> 6;
  const int bid  = blockIdx.x;

  int*            flags = (int*)ws;                         // [4][64] real + [4][64] scratch
  unsigned short* h0    = (unsigned short*)(ws + 4096);     // 24 x 64x1024 bf16
  unsigned short* h1    = (unsigned short*)(ws + 3149824);  // 24 x 64x1024 bf16
  float*          gxw   = (float*)(ws + 6295552);           // 3 x 64x(64x48) f32

  int role, p;
  if (bid < 64)       { role = 0; p = bid; }
  else if (bid < 128) { role = 1; p = bid - 64; }
  else if (bid < 192) { role = 2; p = bid - 128; }
  else                { role = 3; p = bid - 192; }
  const int base = p * 16;

  unsigned short* frag = (unsigned short*)smem;
  float* G   = (float*)(smem + 98304);    // 2 x 64x49 f32 (double buffer)
  float* hm  = (float*)(smem + 123392);   // fp32 master state
  float* bi  = (float*)(smem + 127488);
  float* bh  = (float*)(smem + 127680);
  volatile int* ready  = (volatile int*)(smem + 127872);  // [9]
  volatile int* gdone  = (volatile int*)(smem + 127936);  // [4]
  volatile int* ewflag = (volatile int*)(smem + 127952);  // [3]
  volatile int* gxst   = (volatile int*)(smem + 127968);  // [3]
  volatile int* ewdone = (volatile int*)(smem + 127984);  // [1]
  float* gxl = (float*)(smem + 128000);   // S2: 2 x 64x48 f32 (double buffer)
  float* bo  = (float*)(smem + 32768);    // S3 only (past its 32KB frags)

  int* fS0 = flags;       int* fS1 = flags + 64;
  int* fS2 = flags + 128; int* fS3 = flags + 192;

  // ---------------- one-time init: weights -> LDS bf16 B-fragments ---------
  if (role < 3) {
    const float* W = (role == 0) ? Whh0 : (role == 1) ? Wih1 : Whh1;
    for (int q = tid; q < 6144; q += 512) {
      int c = q % 48; int r2 = q / 48; int grp = r2 & 3; int kb = r2 >> 2;
      int g = c >> 4, u = c & 15;
      unsigned short* dst = frag + (kb*3 + g)*512 + (grp*16 + u)*8;
      const float* s = W + (size_t)(g*H + base + u)*H + kb*32 + grp*8;
      #pragma unroll
      for (int j = 0; j < 8; ++j) dst[j] = f2bf(s[j]);
    }
  }
  if (role == 0 || role == 2) {
    const float* bip = (role == 0) ? bih0 : bih1;
    const float* bhp = (role == 0) ? bhh0 : bhh1;
    if (tid < 48) {
      int g = tid >> 4, u = tid & 15;
      bi[tid] = bip[g*H + base + u];
      bh[tid] = bhp[g*H + base + u];
    }
  } else if (role == 3) {
    for (int q = tid; q < 2048; q += 512) {
      int c = q & 15, grp = (q >> 4) & 3, kb = q >> 6;
      unsigned short* dst = frag + kb*512 + (grp*16 + c)*8;
      const float* s = Wout + (size_t)(base + c)*H + kb*32 + grp*8;
      #pragma unroll
      for (int j = 0; j < 8; ++j) dst[j] = f2bf(s[j]);
    }
    if (tid < 16) bo[tid] = bout[base + tid];
  }

  // =============== PASS A (ablated, bypass loads) then PASS B (real) =======
  for (int pass = 0; pass < 2; ++pass) {
    const bool abl = (pass == 0);
    int* fw = abl ? (flags + 256) : flags;       // flag WRITE base this pass

    // ---- per-pass init (barrier first: prior pass fully done in-block) ----
    __syncthreads();
    if (tid < 9) ready[tid] = -1;
    if (tid == 0) {
      gdone[0] = gdone[1] = gdone[2] = gdone[3] = -1;
      ewflag[0] = ewflag[1] = ewflag[2] = -1;
      gxst[0] = gxst[1] = gxst[2] = -1;
      *ewdone = -1;
    }
    if (!abl && (role == 0 || role == 2)) {
      // re-init fp32 master state + publish h^{-1} in slot 23
      unsigned short* hb = (role == 0) ? h0 : h1;
      for (int q = tid; q < 1024; q += 512) {
        int b = q >> 4, u = q & 15;
        float v = z[b*H + base + u];
        hm[q] = v;
        st_u16(&hb[(NSLOT-1)*65536 + b*H + base + u], f2bf(v));
      }
    }
    WAITV(0);
    if (!abl) l2inv();    // clear any ablated-era / stale lines before real pass
    __syncthreads();
    if (!abl && tid == 0) st_i32(&flags[role*64 + p], 1);  // data-step -1 done

    if (role < 3) {
      unsigned short* hsrc = (role == 2) ? h1 : h0;   // GEMM A source
      if (w < 4) {
        // ---- GEMM waves: free-running, double-buffered G ----
        const int ldg = (role == 1) ? 48 : 49;
        const int dt  = (role == 1) ? 0 : 1;          // A slot: t-dt
        for (int t = 0; t < 1024; ++t) {
          if (!abl && w == 0 && (t & 15) == 0) l2inv();  // sparse aligned inv
          while (*ewdone < t - 2) {}
          MEMBAR;
          const unsigned short* arow = hsrc + SLOT(t - dt)*65536
                                       + (w*16 + (lane&15))*H + ((lane>>4)*8);
          if (abl) gemm48<true >(arow, frag + lane*8, ready, t, G + (t&1)*3136, ldg, lane, w);
          else     gemm48<false>(arow, frag + lane*8, ready, t, G + (t&1)*3136, ldg, lane, w);
          MEMBAR;
          gdone[w] = t;
        }
      } else if (w == 7) {
        if (abl) {
          // ABLATION: release everything immediately; no cross-block waits
          if (lane < 9) ready[lane] = 1023;
        } else {
          for (int t = 0; t < 1024; ++t) {
            if (role == 0)      poller(fS0, t+1, nullptr, 0, fS1, 64, t-1, ready, t, lane);
            else if (role == 1) poller(fS0, t+2, nullptr, 0, fS2, 64, t-1, ready, t, lane);
            else                poller(fS2, t+1, &fS1[p], t+2, fS3, 8, t-1, ready, t, lane);
          }
        }
      } else {
        // ---- ew waves 4-6 ----
        const int wv = w - 4;
        const int ewt = wv*64 + lane;                 // 0..191
        int* fme = fw + role*64 + p;
        for (int t = 0; t < 1024; ++t) {
          if (role == 2) {
            // stage gx^t -> gxl[t&1] (coalesced, off the GEMM waves)
            while (ready[8] < t) {}
            MEMBAR;
            const float* gxp = gxw + (size_t)(t % 3)*196608 + p*3072
                               + wv*1024 + lane*16;
            f32x4 ga = gldf(gxp), gb = gldf(gxp + 4),
                  gc = gldf(gxp + 8), gd = gldf(gxp + 12);
            WAITV(0);
            asm volatile("" : "+v"(ga), "+v"(gb), "+v"(gc), "+v"(gd));
            float* dstl = gxl + (t&1)*3072 + wv*1024 + lane*16;
            *(f32x4*)(dstl)      = ga; *(f32x4*)(dstl + 4)  = gb;
            *(f32x4*)(dstl + 8)  = gc; *(f32x4*)(dstl + 12) = gd;
            MEMBAR;
            gxst[wv] = t;
            while (gxst[0] < t || gxst[1] < t || gxst[2] < t) {}
            MEMBAR;
          }
          while (gdone[0] < t || gdone[1] < t || gdone[2] < t || gdone[3] < t) {}
          MEMBAR;
          float* Gt = G + (t&1)*3136;
          if (role == 1) {
            // dump Gx to global
            float* dst = gxw + (size_t)(t % 3)*196608 + p*3072;
            for (int c2 = ewt; c2 < 768; c2 += 192)
              gst16f(*(f32x4*)(Gt + c2*4), dst + c2*4);
          } else {
            float* gx2 = gxl + (t&1)*3072;
            unsigned short* hdst = hsrc + SLOT(t)*65536;
            for (int q = ewt; q < 512; q += 192) {
              int b = q >> 3, u2 = (q & 7) * 2;
              unsigned short pk[2];
              #pragma unroll
              for (int j = 0; j < 2; ++j) {
                int u = u2 + j;
                float xr, xz, xn;
                if (role == 0) {                 // gx = b_ih_0 (x == 0)
                  xr = bi[u]; xz = bi[16 + u]; xn = bi[32 + u];
                } else {
                  xr = gx2[b*48 + u]      + bi[u];
                  xz = gx2[b*48 + 16 + u] + bi[16 + u];
                  xn = gx2[b*48 + 32 + u] + bi[32 + u];
                }
                float hr = Gt[b*49 + u]      + bh[u];
                float hz = Gt[b*49 + 16 + u] + bh[16 + u];
                float hn = Gt[b*49 + 32 + u] + bh[32 + u];
                float r  = sigm(xr + hr);
                float zg = sigm(xz + hz);
                float n  = tanhf(xn + r * hn);
                int idx = b*16 + u;
                float hp = hm[idx];
                float hv = (1.f - zg) * n + zg * hp;
                hm[idx] = hv;
                pk[j] = f2bf(hv);
              }
              gst4u((unsigned)pk[0] | ((unsigned)pk[1] << 16),
                    &hdst[b*H + base + u2]);
            }
          }
          WAITV(0);
          MEMBAR;
          ewflag[wv] = t;
          if (wv == 0) {
            while (ewflag[1] < t || ewflag[2] < t) {}
            MEMBAR;
            if (lane == 0) st_i32(fme, t + 2);
            MEMBAR;
            *ewdone = t;
          }
        }
      }
    } else {
      // ---- S3: per-step block barrier kept (as R11) ----
      for (int t = 0; t < 1024; ++t) {
        if (w == 7) {
          if (abl) {
            if (t == 0 && lane < 9) ready[lane] = 1023;
          } else {
            poller(fS2, t+2, nullptr, 0, nullptr, 0, 0, ready, t, lane);
          }
        } else if (w < 4) {
          if (!abl && w == 0 && (t & 15) == 0) l2inv();
          const unsigned short* arow = h1 + (t % NSLOT)*65536
                                       + (w*16 + (lane&15))*H + ((lane>>4)*8);
          if (abl) s3_gemm<true >(arow, frag + lane*8, ready, t, bo, out, base, lane, w);
          else     s3_gemm<false>(arow, frag + lane*8, ready, t, bo, out, base, lane, w);
        }
        WAITV(0);
        __syncthreads();
        if (tid == 0) st_i32(&fw[192 + p], t + 2);
      }
    }
  }
}

extern "C" void kernel_launch(void* const* d_in, const int* in_sizes, int n_in,
                              void* d_out, int out_size, void* d_ws, size_t ws_size,
                              hipStream_t stream) {
  const float* z    = (const float*)d_in[0];
  // d_in[1] = seq_len (==1024, hard-coded); d_in[2] = W_ih_0 (unused: x0==0)
  const float* Whh0 = (const float*)d_in[3];
  const float* bih0 = (const float*)d_in[4];
  const float* bhh0 = (const float*)d_in[5];
  const float* Wih1 = (const float*)d_in[6];
  const float* Whh1 = (const float*)d_in[7];
  const float* bih1 = (const float*)d_in[8];
  const float* bhh1 = (const float*)d_in[9];
  const float* Wout = (const float*)d_in[10];
  const float* bout = (const float*)d_in[11];
  float* out = (float*)d_out;
  char* ws = (char*)d_ws;

  hipFuncSetAttribute((const void*)gru_pipeline,
                      hipFuncAttributeMaxDynamicSharedMemorySize, SMEM_BYTES);
  hipMemsetAsync(d_ws, 0, 4096, stream);   // flags (real + scratch)

  void* args[] = { (void*)&z, (void*)&Whh0, (void*)&bih0, (void*)&bhh0,
                   (void*)&Wih1, (void*)&Whh1, (void*)&bih1, (void*)&bhh1,
                   (void*)&Wout, (void*)&bout, (void*)&out, (void*)&ws };
  hipLaunchCooperativeKernel((void*)gru_pipeline, dim3(NBLK), dim3(512),
                             args, SMEM_BYTES, stream);
}

// Round 5
// 17098.439 us; speedup vs baseline: 1.0025x; 1.0025x over previous
//
#include <hip/hip_runtime.h>

// DecoderGRU: 2-layer GRU (B=64, H=1024, T=1024, OUT=128) + output projection.
// R14 = two-pass instrument (as R13), ONE controlled change: pass B GEMM
// A-loads are PLAIN (L1+L2 cached) instead of sc0. R13 split the 11.2us step
// into ~5.5us data floor (bypass loads; matches 128KB/step/CU @ ~8.5B/cyc
// MSHR model) + ~5.7us sync chain. R11 (sc0 loads) was null but sc0 may not
// cache on gfx950 (miss-evict), or producer sc0sc1 write-through may
// invalidate L2 copies. This round: pass A = bypass loads (calibrated 5.6ms),
// pass B = R11 protocol with PLAIN loads + same 16-step aligned l2inv.
// realB = dur - 5.6ms.
// Staleness proof (L1 incl.): buffer_inv clears CU L1+L2; GEMM waves within
// ~3 steps of each other (ewdone gating) -> max line age between aligned invs
// <= 19 slots < 24-slot reuse. ew sc0sc1 stores write through (no stale
// self-lines). Pass-A garbage lines cleared by pass-B prologue l2inv.
// Pre-commit: dur 13-15.5ms -> ship plain-load pipeline standalone next;
// dur ~17ms -> caching dead, attack the 5.7us sync chain next.
//   S0 (blk 0-63):   h0^t = GRU0(h0^{t-1})        [16 units/blk]
//   S1 (blk 64-127): Gx^t = y0^t @ W_ih1^T        [16 units/blk]
//   S2 (blk 128-191): h1^t = GRU1(Gx^t, h1^{t-1}) [16 units/blk]
//   S3 (blk 192-199): out^t = y1^t @ W_out^T + b  [16 cols/blk]

#define NBLK 200
#define SMEM_BYTES 152576
#define H 1024
#define T 1024
#define NSLOT 24
#define SLOT(k) (((k) + NSLOT) % NSLOT)
#define MEMBAR asm volatile("" ::: "memory")

typedef short s16x8 __attribute__((ext_vector_type(8)));
typedef float f32x4 __attribute__((ext_vector_type(4)));

__device__ __forceinline__ unsigned short f2bf(float f) {
  union { float f; unsigned u; } v; v.f = f;
  return (unsigned short)((v.u + 0x7FFFu + ((v.u >> 16) & 1u)) >> 16);
}
__device__ __forceinline__ float sigm(float x) { return 1.f / (1.f + __expf(-x)); }

__device__ __forceinline__ void st_u16(void* p, unsigned short v) {
  __hip_atomic_store((unsigned short*)p, v, __ATOMIC_RELAXED, __HIP_MEMORY_SCOPE_AGENT);
}
__device__ __forceinline__ void st_i32(int* p, int v) {
  __hip_atomic_store(p, v, __ATOMIC_RELAXED, __HIP_MEMORY_SCOPE_AGENT);
}
__device__ __forceinline__ int ld_i32(const int* p) {
  return __hip_atomic_load(p, __ATOMIC_RELAXED, __HIP_MEMORY_SCOPE_AGENT);
}

__device__ __forceinline__ void l2inv() {
  __builtin_amdgcn_fence(__ATOMIC_ACQUIRE, "agent");
}

// PLAIN (L1+L2 cached) and Bypass (sc0 sc1) load flavors.
#define GLDP(d, p, off) \
  asm volatile("global_load_dwordx4 %0, %1, off offset:" #off \
               : "=v"(d) : "v"(p))
#define GLDB(d, p, off) \
  asm volatile("global_load_dwordx4 %0, %1, off offset:" #off " sc0 sc1" \
               : "=v"(d) : "v"(p))
#define WAITV(n) asm volatile("s_waitcnt vmcnt(" #n ")" ::: "memory")
#define TIE4(A) \
  asm volatile("" : "+v"(A[0]),"+v"(A[1]),"+v"(A[2]),"+v"(A[3]))

template<bool BYP>
__device__ __forceinline__ void gldg(s16x8 (&A)[4], const unsigned short* p) {
  if (BYP) { GLDB(A[0],p,0); GLDB(A[1],p,64); GLDB(A[2],p,128); GLDB(A[3],p,192); }
  else     { GLDP(A[0],p,0); GLDP(A[1],p,64); GLDP(A[2],p,128); GLDP(A[3],p,192); }
}

// ---- coherent (L2-bypass) stores + gx loads: unchanged publish protocol --
__device__ __forceinline__ void gst16f(f32x4 v, void* p) {
  asm volatile("global_store_dwordx4 %0, %1, off sc0 sc1" :: "v"(p), "v"(v) : "memory");
}
__device__ __forceinline__ void gst4(float v, void* p) {
  asm volatile("global_store_dword %0, %1, off sc0 sc1" :: "v"(p), "v"(v) : "memory");
}
__device__ __forceinline__ void gst4u(unsigned v, void* p) {
  asm volatile("global_store_dword %0, %1, off sc0 sc1" :: "v"(p), "v"(v) : "memory");
}
__device__ __forceinline__ f32x4 gldf(const float* p) {
  f32x4 d;
  asm volatile("global_load_dwordx4 %0, %1, off sc0 sc1" : "=v"(d) : "v"(p));
  return d;
}

// Wave-7 poller, 2-deep pipelined (identical to R9-R13). Real pass only.
__device__ __forceinline__ void poller(const int* fd, int dtgt,
                                       const int* fgx, int gtgt,
                                       const int* fa, int na, int atgt,
                                       volatile int* ready, int t, int lane) {
  {
    const int* fp = fd + lane;
    int v = ld_i32(fp);
    for (;;) {
      int vn = ld_i32(fp);
      unsigned long long m = __ballot(v >= dtgt);
      if (lane < 8 && ((m >> (8 * lane)) & 0xFFull) == 0xFFull) ready[lane] = t;
      if (m == ~0ull) break;
      v = vn;
    }
  }
  if (fgx) {
    int v = (lane == 0) ? ld_i32(fgx) : 0x7fffffff;
    for (;;) {
      int vn = (lane == 0) ? ld_i32(fgx) : 0x7fffffff;
      if (__ballot(v < gtgt) == 0ull) break;
      v = vn;
    }
    if (lane == 0) ready[8] = t;
  }
  if (fa) {
    bool act = lane < na;
    const int* fp = fa + (act ? lane : 0);
    int v = act ? ld_i32(fp) : atgt;
    for (;;) {
      int vn = act ? ld_i32(fp) : atgt;
      if (__ballot(v < atgt) == 0ull) break;
      v = vn;
    }
  }
}

#define MF3(Ap, g) { \
  _Pragma("unroll") \
  for (int i = 0; i < 4; ++i) { int kb = (g)*4 + i; \
    s16x8 b0 = *(const s16x8*)(bb + (kb*3+0)*512); \
    s16x8 b1 = *(const s16x8*)(bb + (kb*3+1)*512); \
    s16x8 b2 = *(const s16x8*)(bb + (kb*3+2)*512); \
    a0 = __builtin_amdgcn_mfma_f32_16x16x32_bf16(Ap[i], b0, a0, 0, 0, 0); \
    a1 = __builtin_amdgcn_mfma_f32_16x16x32_bf16(Ap[i], b1, a1, 0, 0, 0); \
    a2 = __builtin_amdgcn_mfma_f32_16x16x32_bf16(Ap[i], b2, a2, 0, 0, 0); } }

#define MF1(Ap, g) { \
  _Pragma("unroll") \
  for (int i = 0; i < 4; ++i) { int kb = (g)*4 + i; \
    s16x8 b0 = *(const s16x8*)(bb + kb*512); \
    a0 = __builtin_amdgcn_mfma_f32_16x16x32_bf16(Ap[i], b0, a0, 0, 0, 0); } }

// N=48 GEMM, group-pipelined (identical compute to R11/R13).
template<bool BYP>
__device__ __forceinline__ void gemm48(const unsigned short* arow,
                                       const unsigned short* bb,
                                       volatile int* ready, int t,
                                       float* G, int ldg, int lane, int w) {
  f32x4 a0 = {0,0,0,0}, a1 = {0,0,0,0}, a2 = {0,0,0,0};
  s16x8 A0[4], A1[4];
  while (ready[0] < t) {}
  MEMBAR;
  gldg<BYP>(A0, arow);
  while (ready[1] < t) {}
  MEMBAR;
  gldg<BYP>(A1, arow + 128);
  #pragma unroll
  for (int g2 = 1; g2 < 4; ++g2) {
    WAITV(4); TIE4(A0); MF3(A0, 2*g2 - 2);
    while (ready[2*g2] < t) {}
    MEMBAR;
    gldg<BYP>(A0, arow + g2*256);
    WAITV(4); TIE4(A1); MF3(A1, 2*g2 - 1);
    while (ready[2*g2 + 1] < t) {}
    MEMBAR;
    gldg<BYP>(A1, arow + g2*256 + 128);
  }
  WAITV(4); TIE4(A0); MF3(A0, 6);
  WAITV(0); TIE4(A1); MF3(A1, 7);
  int col = lane & 15, r0 = (lane >> 4) * 4;
  #pragma unroll
  for (int r = 0; r < 4; ++r) {
    int brow = w*16 + r0 + r;
    G[brow*ldg +      col] = a0[r];
    G[brow*ldg + 16 + col] = a1[r];
    G[brow*ldg + 32 + col] = a2[r];
  }
}

// S3 GEMM step (N=16), identical compute to R11/R13.
template<bool BYP>
__device__ __forceinline__ void s3_gemm(const unsigned short* arow,
                                        const unsigned short* bb,
                                        volatile int* ready, int t,
                                        const float* bo, float* out,
                                        int base, int lane, int w) {
  f32x4 a0 = {0,0,0,0};
  s16x8 A0[4], A1[4];
  while (ready[0] < t) {}
  MEMBAR;
  gldg<BYP>(A0, arow);
  while (ready[1] < t) {}
  MEMBAR;
  gldg<BYP>(A1, arow + 128);
  #pragma unroll
  for (int g2i = 1; g2i < 4; ++g2i) {
    WAITV(4); TIE4(A0); MF1(A0, 2*g2i - 2);
    while (ready[2*g2i] < t) {}
    MEMBAR;
    gldg<BYP>(A0, arow + g2i*256);
    WAITV(4); TIE4(A1); MF1(A1, 2*g2i - 1);
    while (ready[2*g2i + 1] < t) {}
    MEMBAR;
    gldg<BYP>(A1, arow + g2i*256 + 128);
  }
  WAITV(4); TIE4(A0); MF1(A0, 6);
  WAITV(0); TIE4(A1); MF1(A1, 7);
  int col = lane & 15, r0 = (lane >> 4) * 4;
  #pragma unroll
  for (int r = 0; r < 4; ++r) {
    int brow = w*16 + r0 + r;
    gst4(a0[r] + bo[col], out + (size_t)(brow*T + t)*128 + base + col);
  }
}

extern "C" __global__ void __launch_bounds__(512, 1)
gru_pipeline(const float* __restrict__ z,
             const float* __restrict__ Whh0,
             const float* __restrict__ bih0, const float* __restrict__ bhh0,
             const float* __restrict__ Wih1, const float* __restrict__ Whh1,
             const float* __restrict__ bih1, const float* __restrict__ bhh1,
             const float* __restrict__ Wout, const float* __restrict__ bout,
             float* __restrict__ out, char* __restrict__ ws)
{
  extern __shared__ char smem[];
  const int tid  = threadIdx.x;
  const int lane = tid & 63;
  const int w    = tid >> 6;
  const int bid  = blockIdx.x;

  int*            flags = (int*)ws;                         // [4][64] real + [4][64] scratch
  unsigned short* h0    = (unsigned short*)(ws + 4096);     // 24 x 64x1024 bf16
  unsigned short* h1    = (unsigned short*)(ws + 3149824);  // 24 x 64x1024 bf16
  float*          gxw   = (float*)(ws + 6295552);           // 3 x 64x(64x48) f32

  int role, p;
  if (bid < 64)       { role = 0; p = bid; }
  else if (bid < 128) { role = 1; p = bid - 64; }
  else if (bid < 192) { role = 2; p = bid - 128; }
  else                { role = 3; p = bid - 192; }
  const int base = p * 16;

  unsigned short* frag = (unsigned short*)smem;
  float* G   = (float*)(smem + 98304);    // 2 x 64x49 f32 (double buffer)
  float* hm  = (float*)(smem + 123392);   // fp32 master state
  float* bi  = (float*)(smem + 127488);
  float* bh  = (float*)(smem + 127680);
  volatile int* ready  = (volatile int*)(smem + 127872);  // [9]
  volatile int* gdone  = (volatile int*)(smem + 127936);  // [4]
  volatile int* ewflag = (volatile int*)(smem + 127952);  // [3]
  volatile int* gxst   = (volatile int*)(smem + 127968);  // [3]
  volatile int* ewdone = (volatile int*)(smem + 127984);  // [1]
  float* gxl = (float*)(smem + 128000);   // S2: 2 x 64x48 f32 (double buffer)
  float* bo  = (float*)(smem + 32768);    // S3 only (past its 32KB frags)

  int* fS0 = flags;       int* fS1 = flags + 64;
  int* fS2 = flags + 128; int* fS3 = flags + 192;

  // ---------------- one-time init: weights -> LDS bf16 B-fragments ---------
  if (role < 3) {
    const float* W = (role == 0) ? Whh0 : (role == 1) ? Wih1 : Whh1;
    for (int q = tid; q < 6144; q += 512) {
      int c = q % 48; int r2 = q / 48; int grp = r2 & 3; int kb = r2 >> 2;
      int g = c >> 4, u = c & 15;
      unsigned short* dst = frag + (kb*3 + g)*512 + (grp*16 + u)*8;
      const float* s = W + (size_t)(g*H + base + u)*H + kb*32 + grp*8;
      #pragma unroll
      for (int j = 0; j < 8; ++j) dst[j] = f2bf(s[j]);
    }
  }
  if (role == 0 || role == 2) {
    const float* bip = (role == 0) ? bih0 : bih1;
    const float* bhp = (role == 0) ? bhh0 : bhh1;
    if (tid < 48) {
      int g = tid >> 4, u = tid & 15;
      bi[tid] = bip[g*H + base + u];
      bh[tid] = bhp[g*H + base + u];
    }
  } else if (role == 3) {
    for (int q = tid; q < 2048; q += 512) {
      int c = q & 15, grp = (q >> 4) & 3, kb = q >> 6;
      unsigned short* dst = frag + kb*512 + (grp*16 + c)*8;
      const float* s = Wout + (size_t)(base + c)*H + kb*32 + grp*8;
      #pragma unroll
      for (int j = 0; j < 8; ++j) dst[j] = f2bf(s[j]);
    }
    if (tid < 16) bo[tid] = bout[base + tid];
  }

  // =============== PASS A (ablated, bypass loads) then PASS B (real) =======
  for (int pass = 0; pass < 2; ++pass) {
    const bool abl = (pass == 0);
    int* fw = abl ? (flags + 256) : flags;       // flag WRITE base this pass

    // ---- per-pass init (barrier first: prior pass fully done in-block) ----
    __syncthreads();
    if (tid < 9) ready[tid] = -1;
    if (tid == 0) {
      gdone[0] = gdone[1] = gdone[2] = gdone[3] = -1;
      ewflag[0] = ewflag[1] = ewflag[2] = -1;
      gxst[0] = gxst[1] = gxst[2] = -1;
      *ewdone = -1;
    }
    if (!abl && (role == 0 || role == 2)) {
      // re-init fp32 master state + publish h^{-1} in slot 23
      unsigned short* hb = (role == 0) ? h0 : h1;
      for (int q = tid; q < 1024; q += 512) {
        int b = q >> 4, u = q & 15;
        float v = z[b*H + base + u];
        hm[q] = v;
        st_u16(&hb[(NSLOT-1)*65536 + b*H + base + u], f2bf(v));
      }
    }
    WAITV(0);
    if (!abl) l2inv();    // clear ablated-era garbage from L1/L2 before real pass
    __syncthreads();
    if (!abl && tid == 0) st_i32(&flags[role*64 + p], 1);  // data-step -1 done

    if (role < 3) {
      unsigned short* hsrc = (role == 2) ? h1 : h0;   // GEMM A source
      if (w < 4) {
        // ---- GEMM waves: free-running, double-buffered G ----
        const int ldg = (role == 1) ? 48 : 49;
        const int dt  = (role == 1) ? 0 : 1;          // A slot: t-dt
        for (int t = 0; t < 1024; ++t) {
          if (!abl && w == 0 && (t & 15) == 0) l2inv();  // sparse aligned inv
          while (*ewdone < t - 2) {}
          MEMBAR;
          const unsigned short* arow = hsrc + SLOT(t - dt)*65536
                                       + (w*16 + (lane&15))*H + ((lane>>4)*8);
          if (abl) gemm48<true >(arow, frag + lane*8, ready, t, G + (t&1)*3136, ldg, lane, w);
          else     gemm48<false>(arow, frag + lane*8, ready, t, G + (t&1)*3136, ldg, lane, w);
          MEMBAR;
          gdone[w] = t;
        }
      } else if (w == 7) {
        if (abl) {
          // ABLATION: release everything immediately; no cross-block waits
          if (lane < 9) ready[lane] = 1023;
        } else {
          for (int t = 0; t < 1024; ++t) {
            if (role == 0)      poller(fS0, t+1, nullptr, 0, fS1, 64, t-1, ready, t, lane);
            else if (role == 1) poller(fS0, t+2, nullptr, 0, fS2, 64, t-1, ready, t, lane);
            else                poller(fS2, t+1, &fS1[p], t+2, fS3, 8, t-1, ready, t, lane);
          }
        }
      } else {
        // ---- ew waves 4-6 ----
        const int wv = w - 4;
        const int ewt = wv*64 + lane;                 // 0..191
        int* fme = fw + role*64 + p;
        for (int t = 0; t < 1024; ++t) {
          if (role == 2) {
            // stage gx^t -> gxl[t&1] (coalesced, off the GEMM waves)
            while (ready[8] < t) {}
            MEMBAR;
            const float* gxp = gxw + (size_t)(t % 3)*196608 + p*3072
                               + wv*1024 + lane*16;
            f32x4 ga = gldf(gxp), gb = gldf(gxp + 4),
                  gc = gldf(gxp + 8), gd = gldf(gxp + 12);
            WAITV(0);
            asm volatile("" : "+v"(ga), "+v"(gb), "+v"(gc), "+v"(gd));
            float* dstl = gxl + (t&1)*3072 + wv*1024 + lane*16;
            *(f32x4*)(dstl)      = ga; *(f32x4*)(dstl + 4)  = gb;
            *(f32x4*)(dstl + 8)  = gc; *(f32x4*)(dstl + 12) = gd;
            MEMBAR;
            gxst[wv] = t;
            while (gxst[0] < t || gxst[1] < t || gxst[2] < t) {}
            MEMBAR;
          }
          while (gdone[0] < t || gdone[1] < t || gdone[2] < t || gdone[3] < t) {}
          MEMBAR;
          float* Gt = G + (t&1)*3136;
          if (role == 1) {
            // dump Gx to global
            float* dst = gxw + (size_t)(t % 3)*196608 + p*3072;
            for (int c2 = ewt; c2 < 768; c2 += 192)
              gst16f(*(f32x4*)(Gt + c2*4), dst + c2*4);
          } else {
            float* gx2 = gxl + (t&1)*3072;
            unsigned short* hdst = hsrc + SLOT(t)*65536;
            for (int q = ewt; q < 512; q += 192) {
              int b = q >> 3, u2 = (q & 7) * 2;
              unsigned short pk[2];
              #pragma unroll
              for (int j = 0; j < 2; ++j) {
                int u = u2 + j;
                float xr, xz, xn;
                if (role == 0) {                 // gx = b_ih_0 (x == 0)
                  xr = bi[u]; xz = bi[16 + u]; xn = bi[32 + u];
                } else {
                  xr = gx2[b*48 + u]      + bi[u];
                  xz = gx2[b*48 + 16 + u] + bi[16 + u];
                  xn = gx2[b*48 + 32 + u] + bi[32 + u];
                }
                float hr = Gt[b*49 + u]      + bh[u];
                float hz = Gt[b*49 + 16 + u] + bh[16 + u];
                float hn = Gt[b*49 + 32 + u] + bh[32 + u];
                float r  = sigm(xr + hr);
                float zg = sigm(xz + hz);
                float n  = tanhf(xn + r * hn);
                int idx = b*16 + u;
                float hp = hm[idx];
                float hv = (1.f - zg) * n + zg * hp;
                hm[idx] = hv;
                pk[j] = f2bf(hv);
              }
              gst4u((unsigned)pk[0] | ((unsigned)pk[1] << 16),
                    &hdst[b*H + base + u2]);
            }
          }
          WAITV(0);
          MEMBAR;
          ewflag[wv] = t;
          if (wv == 0) {
            while (ewflag[1] < t || ewflag[2] < t) {}
            MEMBAR;
            if (lane == 0) st_i32(fme, t + 2);
            MEMBAR;
            *ewdone = t;
          }
        }
      }
    } else {
      // ---- S3: per-step block barrier kept (as R11) ----
      for (int t = 0; t < 1024; ++t) {
        if (w == 7) {
          if (abl) {
            if (t == 0 && lane < 9) ready[lane] = 1023;
          } else {
            poller(fS2, t+2, nullptr, 0, nullptr, 0, 0, ready, t, lane);
          }
        } else if (w < 4) {
          if (!abl && w == 0 && (t & 15) == 0) l2inv();
          const unsigned short* arow = h1 + (t % NSLOT)*65536
                                       + (w*16 + (lane&15))*H + ((lane>>4)*8);
          if (abl) s3_gemm<true >(arow, frag + lane*8, ready, t, bo, out, base, lane, w);
          else     s3_gemm<false>(arow, frag + lane*8, ready, t, bo, out, base, lane, w);
        }
        WAITV(0);
        __syncthreads();
        if (tid == 0) st_i32(&fw[192 + p], t + 2);
      }
    }
  }
}

extern "C" void kernel_launch(void* const* d_in, const int* in_sizes, int n_in,
                              void* d_out, int out_size, void* d_ws, size_t ws_size,
                              hipStream_t stream) {
  const float* z    = (const float*)d_in[0];
  // d_in[1] = seq_len (==1024, hard-coded); d_in[2] = W_ih_0 (unused: x0==0)
  const float* Whh0 = (const float*)d_in[3];
  const float* bih0 = (const float*)d_in[4];
  const float* bhh0 = (const float*)d_in[5];
  const float* Wih1 = (const float*)d_in[6];
  const float* Whh1 = (const float*)d_in[7];
  const float* bih1 = (const float*)d_in[8];
  const float* bhh1 = (const float*)d_in[9];
  const float* Wout = (const float*)d_in[10];
  const float* bout = (const float*)d_in[11];
  float* out = (float*)d_out;
  char* ws = (char*)d_ws;

  hipFuncSetAttribute((const void*)gru_pipeline,
                      hipFuncAttributeMaxDynamicSharedMemorySize, SMEM_BYTES);
  hipMemsetAsync(d_ws, 0, 4096, stream);   // flags (real + scratch)

  void* args[] = { (void*)&z, (void*)&Whh0, (void*)&bih0, (void*)&bhh0,
                   (void*)&Wih1, (void*)&Whh1, (void*)&bih1, (void*)&bhh1,
                   (void*)&Wout, (void*)&bout, (void*)&out, (void*)&ws };
  hipLaunchCooperativeKernel((void*)gru_pipeline, dim3(NBLK), dim3(512),
                             args, SMEM_BYTES, stream);
}

// Round 6
// 12014.674 us; speedup vs baseline: 1.4266x; 1.4231x over previous
//
#include <hip/hip_runtime.h>

// DecoderGRU: 2-layer GRU (B=64, H=1024, T=1024, OUT=128) + output projection.
// R15 = DEEP-SLOT DECOUPLING + 4-DEEP LOAD PIPELINE + WIDE H-STORES.
// R13/R14 split the 11.2us step: ~5.5us bypass-load data floor + ~5.7us sync.
// R10/R11/R14 proved NO cache flavor helps (write-through producers defeat
// L2 reuse). This round attacks both remaining terms:
//  1) Anti-runahead gates relaxed from t-1 (3-slot relic) to t-14 (h: 16
//     slots) / t-3 (gxw: 5 slots). Upstream stages run ahead; flags arrive
//     EARLY so poll-detect collapses; sync becomes fill, not per-step cost.
//     Slot-capacity proofs: h slot t reused at t+16; readers (S1 step t /
//     S3 step t) proven done by fS1/fS3 >= t+2 >= (t+16)-14. gxw slot t
//     reused at t+5; S2's stage of step t proven done by fS2 >= t+2.
//  2) gemm48 holds 4 load-groups in flight (was 2): 2x outstanding bytes.
//     If the 5.5us floor is per-wave-outstanding-bound -> ~3us; if CU-MSHR
//     capped -> null (falsification read).
//  3) ew h-stores widened 4B->8B dwordx2 (halves store/drain transactions).
// All loads/stores remain sc0 sc1 bypass (proven semantics). No fences.
//   S0 (blk 0-63):   h0^t = GRU0(h0^{t-1})        [16 units/blk]
//   S1 (blk 64-127): Gx^t = y0^t @ W_ih1^T        [16 units/blk]
//   S2 (blk 128-191): h1^t = GRU1(Gx^t, h1^{t-1}) [16 units/blk]
//   S3 (blk 192-199): out^t = y1^t @ W_out^T + b  [16 cols/blk]

#define NBLK 200
#define SMEM_BYTES 152576
#define H 1024
#define T 1024
#define NSLOT 16
#define NGX 5
#define SLOT(k) (((k) + NSLOT) & (NSLOT - 1))
#define MEMBAR asm volatile("" ::: "memory")

typedef short s16x8 __attribute__((ext_vector_type(8)));
typedef float f32x4 __attribute__((ext_vector_type(4)));
typedef unsigned u32x2 __attribute__((ext_vector_type(2)));

__device__ __forceinline__ unsigned short f2bf(float f) {
  union { float f; unsigned u; } v; v.f = f;
  return (unsigned short)((v.u + 0x7FFFu + ((v.u >> 16) & 1u)) >> 16);
}
__device__ __forceinline__ float sigm(float x) { return 1.f / (1.f + __expf(-x)); }

__device__ __forceinline__ void st_u16(void* p, unsigned short v) {
  __hip_atomic_store((unsigned short*)p, v, __ATOMIC_RELAXED, __HIP_MEMORY_SCOPE_AGENT);
}
__device__ __forceinline__ void st_i32(int* p, int v) {
  __hip_atomic_store(p, v, __ATOMIC_RELAXED, __HIP_MEMORY_SCOPE_AGENT);
}
__device__ __forceinline__ int ld_i32(const int* p) {
  return __hip_atomic_load(p, __ATOMIC_RELAXED, __HIP_MEMORY_SCOPE_AGENT);
}

// ---- coalesced device-coherent loads/stores (bypass L1/L2) ---------------
#define GLD(d, p, off) \
  asm volatile("global_load_dwordx4 %0, %1, off offset:" #off " sc0 sc1" \
               : "=v"(d) : "v"(p))
#define GLDG(A, p) GLD(A[0],p,0); GLD(A[1],p,64); GLD(A[2],p,128); GLD(A[3],p,192)
#define WAITV(n) asm volatile("s_waitcnt vmcnt(" #n ")" ::: "memory")
#define TIE4(A) \
  asm volatile("" : "+v"(A[0]),"+v"(A[1]),"+v"(A[2]),"+v"(A[3]))

__device__ __forceinline__ void gst16f(f32x4 v, void* p) {
  asm volatile("global_store_dwordx4 %0, %1, off sc0 sc1" :: "v"(p), "v"(v) : "memory");
}
__device__ __forceinline__ void gst4(float v, void* p) {
  asm volatile("global_store_dword %0, %1, off sc0 sc1" :: "v"(p), "v"(v) : "memory");
}
__device__ __forceinline__ void gst8u(u32x2 v, void* p) {
  asm volatile("global_store_dwordx2 %0, %1, off sc0 sc1" :: "v"(p), "v"(v) : "memory");
}
__device__ __forceinline__ f32x4 gldf(const float* p) {
  f32x4 d;
  asm volatile("global_load_dwordx4 %0, %1, off sc0 sc1" : "=v"(d) : "v"(p));
  return d;
}

// Wave-7 poller, 2-deep pipelined (structure as R9-R14; targets relaxed).
__device__ __forceinline__ void poller(const int* fd, int dtgt,
                                       const int* fgx, int gtgt,
                                       const int* fa, int na, int atgt,
                                       volatile int* ready, int t, int lane) {
  {
    const int* fp = fd + lane;
    int v = ld_i32(fp);
    for (;;) {
      int vn = ld_i32(fp);
      unsigned long long m = __ballot(v >= dtgt);
      if (lane < 8 && ((m >> (8 * lane)) & 0xFFull) == 0xFFull) ready[lane] = t;
      if (m == ~0ull) break;
      v = vn;
    }
  }
  if (fgx) {
    int v = (lane == 0) ? ld_i32(fgx) : 0x7fffffff;
    for (;;) {
      int vn = (lane == 0) ? ld_i32(fgx) : 0x7fffffff;
      if (__ballot(v < gtgt) == 0ull) break;
      v = vn;
    }
    if (lane == 0) ready[8] = t;
  }
  if (fa) {
    bool act = lane < na;
    const int* fp = fa + (act ? lane : 0);
    int v = act ? ld_i32(fp) : atgt;
    for (;;) {
      int vn = act ? ld_i32(fp) : atgt;
      if (__ballot(v < atgt) == 0ull) break;
      v = vn;
    }
  }
}

#define MF3(Ap, g) { \
  _Pragma("unroll") \
  for (int i = 0; i < 4; ++i) { int kb = (g)*4 + i; \
    s16x8 b0 = *(const s16x8*)(bb + (kb*3+0)*512); \
    s16x8 b1 = *(const s16x8*)(bb + (kb*3+1)*512); \
    s16x8 b2 = *(const s16x8*)(bb + (kb*3+2)*512); \
    a0 = __builtin_amdgcn_mfma_f32_16x16x32_bf16(Ap[i], b0, a0, 0, 0, 0); \
    a1 = __builtin_amdgcn_mfma_f32_16x16x32_bf16(Ap[i], b1, a1, 0, 0, 0); \
    a2 = __builtin_amdgcn_mfma_f32_16x16x32_bf16(Ap[i], b2, a2, 0, 0, 0); } }

#define MF1(Ap, g) { \
  _Pragma("unroll") \
  for (int i = 0; i < 4; ++i) { int kb = (g)*4 + i; \
    s16x8 b0 = *(const s16x8*)(bb + kb*512); \
    a0 = __builtin_amdgcn_mfma_f32_16x16x32_bf16(Ap[i], b0, a0, 0, 0, 0); } }

// N=48 GEMM, 4-deep load pipeline (2x in-flight bytes vs R14).
__device__ __forceinline__ void gemm48(const unsigned short* arow,
                                       const unsigned short* bb,
                                       volatile int* ready, int t,
                                       float* G, int ldg, int lane, int w) {
  f32x4 a0 = {0,0,0,0}, a1 = {0,0,0,0}, a2 = {0,0,0,0};
  s16x8 A0[4], A1[4], A2[4], A3[4];
  while (ready[0] < t) {} MEMBAR; GLDG(A0, arow);
  while (ready[1] < t) {} MEMBAR; GLDG(A1, arow + 128);
  while (ready[2] < t) {} MEMBAR; GLDG(A2, arow + 256);
  while (ready[3] < t) {} MEMBAR; GLDG(A3, arow + 384);
  WAITV(12); TIE4(A0); MF3(A0, 0);
  while (ready[4] < t) {} MEMBAR; GLDG(A0, arow + 512);
  WAITV(12); TIE4(A1); MF3(A1, 1);
  while (ready[5] < t) {} MEMBAR; GLDG(A1, arow + 640);
  WAITV(12); TIE4(A2); MF3(A2, 2);
  while (ready[6] < t) {} MEMBAR; GLDG(A2, arow + 768);
  WAITV(12); TIE4(A3); MF3(A3, 3);
  while (ready[7] < t) {} MEMBAR; GLDG(A3, arow + 896);
  WAITV(12); TIE4(A0); MF3(A0, 4);
  WAITV(8);  TIE4(A1); MF3(A1, 5);
  WAITV(4);  TIE4(A2); MF3(A2, 6);
  WAITV(0);  TIE4(A3); MF3(A3, 7);
  int col = lane & 15, r0 = (lane >> 4) * 4;
  #pragma unroll
  for (int r = 0; r < 4; ++r) {
    int brow = w*16 + r0 + r;
    G[brow*ldg +      col] = a0[r];
    G[brow*ldg + 16 + col] = a1[r];
    G[brow*ldg + 32 + col] = a2[r];
  }
}

// S3 GEMM step (N=16), 4-deep load pipeline.
__device__ __forceinline__ void s3_gemm(const unsigned short* arow,
                                        const unsigned short* bb,
                                        volatile int* ready, int t,
                                        const float* bo, float* out,
                                        int base, int lane, int w) {
  f32x4 a0 = {0,0,0,0};
  s16x8 A0[4], A1[4], A2[4], A3[4];
  while (ready[0] < t) {} MEMBAR; GLDG(A0, arow);
  while (ready[1] < t) {} MEMBAR; GLDG(A1, arow + 128);
  while (ready[2] < t) {} MEMBAR; GLDG(A2, arow + 256);
  while (ready[3] < t) {} MEMBAR; GLDG(A3, arow + 384);
  WAITV(12); TIE4(A0); MF1(A0, 0);
  while (ready[4] < t) {} MEMBAR; GLDG(A0, arow + 512);
  WAITV(12); TIE4(A1); MF1(A1, 1);
  while (ready[5] < t) {} MEMBAR; GLDG(A1, arow + 640);
  WAITV(12); TIE4(A2); MF1(A2, 2);
  while (ready[6] < t) {} MEMBAR; GLDG(A2, arow + 768);
  WAITV(12); TIE4(A3); MF1(A3, 3);
  while (ready[7] < t) {} MEMBAR; GLDG(A3, arow + 896);
  WAITV(12); TIE4(A0); MF1(A0, 4);
  WAITV(8);  TIE4(A1); MF1(A1, 5);
  WAITV(4);  TIE4(A2); MF1(A2, 6);
  WAITV(0);  TIE4(A3); MF1(A3, 7);
  int col = lane & 15, r0 = (lane >> 4) * 4;
  #pragma unroll
  for (int r = 0; r < 4; ++r) {
    int brow = w*16 + r0 + r;
    gst4(a0[r] + bo[col], out + (size_t)(brow*T + t)*128 + base + col);
  }
}

extern "C" __global__ void __launch_bounds__(512, 1)
gru_pipeline(const float* __restrict__ z,
             const float* __restrict__ Whh0,
             const float* __restrict__ bih0, const float* __restrict__ bhh0,
             const float* __restrict__ Wih1, const float* __restrict__ Whh1,
             const float* __restrict__ bih1, const float* __restrict__ bhh1,
             const float* __restrict__ Wout, const float* __restrict__ bout,
             float* __restrict__ out, char* __restrict__ ws)
{
  extern __shared__ char smem[];
  const int tid  = threadIdx.x;
  const int lane = tid & 63;
  const int w    = tid >> 6;
  const int bid  = blockIdx.x;

  int*            flags = (int*)ws;                         // [4][64] packed
  unsigned short* h0    = (unsigned short*)(ws + 4096);     // 16 x 64x1024 bf16
  unsigned short* h1    = (unsigned short*)(ws + 2101248);  // 16 x 64x1024 bf16
  float*          gxw   = (float*)(ws + 4198400);           // 5 x 64x(64x48) f32

  int role, p;
  if (bid < 64)       { role = 0; p = bid; }
  else if (bid < 128) { role = 1; p = bid - 64; }
  else if (bid < 192) { role = 2; p = bid - 128; }
  else                { role = 3; p = bid - 192; }
  const int base = p * 16;

  unsigned short* frag = (unsigned short*)smem;
  float* G   = (float*)(smem + 98304);    // 2 x 64x49 f32 (double buffer)
  float* hm  = (float*)(smem + 123392);   // fp32 master state
  float* bi  = (float*)(smem + 127488);
  float* bh  = (float*)(smem + 127680);
  volatile int* ready  = (volatile int*)(smem + 127872);  // [9]
  volatile int* gdone  = (volatile int*)(smem + 127936);  // [4]
  volatile int* ewflag = (volatile int*)(smem + 127952);  // [3]
  volatile int* gxst   = (volatile int*)(smem + 127968);  // [3]
  volatile int* ewdone = (volatile int*)(smem + 127984);  // [1]
  float* gxl = (float*)(smem + 128000);   // S2: 2 x 64x48 f32 (double buffer)
  float* bo  = (float*)(smem + 32768);    // S3 only (past its 32KB frags)

  int* fS0 = flags;       int* fS1 = flags + 64;
  int* fS2 = flags + 128; int* fS3 = flags + 192;

  // ---------------- init: weights -> LDS bf16 B-fragments, prefill ----------
  if (tid < 9) ready[tid] = -1;
  if (tid == 0) {
    gdone[0] = gdone[1] = gdone[2] = gdone[3] = -1;
    ewflag[0] = ewflag[1] = ewflag[2] = -1;
    gxst[0] = gxst[1] = gxst[2] = -1;
    *ewdone = -1;
  }
  if (role < 3) {
    const float* W = (role == 0) ? Whh0 : (role == 1) ? Wih1 : Whh1;
    for (int q = tid; q < 6144; q += 512) {
      int c = q % 48; int r2 = q / 48; int grp = r2 & 3; int kb = r2 >> 2;
      int g = c >> 4, u = c & 15;
      unsigned short* dst = frag + (kb*3 + g)*512 + (grp*16 + u)*8;
      const float* s = W + (size_t)(g*H + base + u)*H + kb*32 + grp*8;
      #pragma unroll
      for (int j = 0; j < 8; ++j) dst[j] = f2bf(s[j]);
    }
  }
  if (role == 0 || role == 2) {
    const float* bip = (role == 0) ? bih0 : bih1;
    const float* bhp = (role == 0) ? bhh0 : bhh1;
    if (tid < 48) {
      int g = tid >> 4, u = tid & 15;
      bi[tid] = bip[g*H + base + u];
      bh[tid] = bhp[g*H + base + u];
    }
    unsigned short* hb = (role == 0) ? h0 : h1;
    for (int q = tid; q < 1024; q += 512) {
      int b = q >> 4, u = q & 15;
      float v = z[b*H + base + u];
      hm[q] = v;
      st_u16(&hb[(NSLOT-1)*65536 + b*H + base + u], f2bf(v));  // h^{-1} slot 15
    }
  } else if (role == 3) {
    for (int q = tid; q < 2048; q += 512) {
      int c = q & 15, grp = (q >> 4) & 3, kb = q >> 6;
      unsigned short* dst = frag + kb*512 + (grp*16 + c)*8;
      const float* s = Wout + (size_t)(base + c)*H + kb*32 + grp*8;
      #pragma unroll
      for (int j = 0; j < 8; ++j) dst[j] = f2bf(s[j]);
    }
    if (tid < 16) bo[tid] = bout[base + tid];
  }
  WAITV(0);
  __syncthreads();
  if (tid == 0) st_i32(&flags[role*64 + p], 1);   // data-step -1 done

  // ---------------- barrier-free steady state (roles 0-2) ------------------
  if (role < 3) {
    unsigned short* hsrc = (role == 2) ? h1 : h0;   // GEMM A source
    if (w < 4) {
      // ---- GEMM waves: free-running, double-buffered G ----
      const int ldg = (role == 1) ? 48 : 49;
      const int dt  = (role == 1) ? 0 : 1;          // A slot: t-dt
      for (int t = 0; t < 1024; ++t) {
        while (*ewdone < t - 2) {}
        MEMBAR;
        const unsigned short* arow = hsrc + SLOT(t - dt)*65536
                                     + (w*16 + (lane&15))*H + ((lane>>4)*8);
        gemm48(arow, frag + lane*8, ready, t, G + (t&1)*3136, ldg, lane, w);
        MEMBAR;
        gdone[w] = t;
      }
    } else if (w == 7) {
      // ---- poller wave: relaxed anti-runahead targets (deep slots) ----
      for (int t = 0; t < 1024; ++t) {
        if (role == 0)      poller(fS0, t+1, nullptr, 0, fS1, 64, t-14, ready, t, lane);
        else if (role == 1) poller(fS0, t+2, nullptr, 0, fS2, 64, t-3,  ready, t, lane);
        else                poller(fS2, t+1, &fS1[p], t+2, fS3, 8, t-14, ready, t, lane);
      }
    } else {
      // ---- ew waves 4-6 ----
      const int wv = w - 4;
      const int ewt = wv*64 + lane;                 // 0..191
      int* fme = flags + role*64 + p;
      for (int t = 0; t < 1024; ++t) {
        if (role == 2) {
          // stage gx^t -> gxl[t&1] (coalesced, off the GEMM waves)
          while (ready[8] < t) {}
          MEMBAR;
          const float* gxp = gxw + (size_t)(t % NGX)*196608 + p*3072
                             + wv*1024 + lane*16;
          f32x4 ga = gldf(gxp), gb = gldf(gxp + 4),
                gc = gldf(gxp + 8), gd = gldf(gxp + 12);
          WAITV(0);
          asm volatile("" : "+v"(ga), "+v"(gb), "+v"(gc), "+v"(gd));
          float* dstl = gxl + (t&1)*3072 + wv*1024 + lane*16;
          *(f32x4*)(dstl)      = ga; *(f32x4*)(dstl + 4)  = gb;
          *(f32x4*)(dstl + 8)  = gc; *(f32x4*)(dstl + 12) = gd;
          MEMBAR;
          gxst[wv] = t;
          while (gxst[0] < t || gxst[1] < t || gxst[2] < t) {}
          MEMBAR;
        }
        while (gdone[0] < t || gdone[1] < t || gdone[2] < t || gdone[3] < t) {}
        MEMBAR;
        float* Gt = G + (t&1)*3136;
        if (role == 1) {
          // dump Gx to global
          float* dst = gxw + (size_t)(t % NGX)*196608 + p*3072;
          for (int c2 = ewt; c2 < 768; c2 += 192)
            gst16f(*(f32x4*)(Gt + c2*4), dst + c2*4);
        } else {
          float* gx2 = gxl + (t&1)*3072;
          unsigned short* hdst = hsrc + SLOT(t)*65536;
          for (int q = ewt; q < 256; q += 192) {
            int b = q >> 2, u0 = (q & 3) * 4;
            unsigned pk2[2];
            #pragma unroll
            for (int jj = 0; jj < 2; ++jj) {
              unsigned short pk[2];
              #pragma unroll
              for (int j = 0; j < 2; ++j) {
                int u = u0 + jj*2 + j;
                float xr, xz, xn;
                if (role == 0) {                 // gx = b_ih_0 (x == 0)
                  xr = bi[u]; xz = bi[16 + u]; xn = bi[32 + u];
                } else {
                  xr = gx2[b*48 + u]      + bi[u];
                  xz = gx2[b*48 + 16 + u] + bi[16 + u];
                  xn = gx2[b*48 + 32 + u] + bi[32 + u];
                }
                float hr = Gt[b*49 + u]      + bh[u];
                float hz = Gt[b*49 + 16 + u] + bh[16 + u];
                float hn = Gt[b*49 + 32 + u] + bh[32 + u];
                float r  = sigm(xr + hr);
                float zg = sigm(xz + hz);
                float n  = tanhf(xn + r * hn);
                int idx = b*16 + u;
                float hp = hm[idx];
                float hv = (1.f - zg) * n + zg * hp;
                hm[idx] = hv;
                pk[j] = f2bf(hv);
              }
              pk2[jj] = (unsigned)pk[0] | ((unsigned)pk[1] << 16);
            }
            u32x2 v2; v2.x = pk2[0]; v2.y = pk2[1];
            gst8u(v2, &hdst[b*H + base + u0]);
          }
        }
        WAITV(0);
        MEMBAR;
        ewflag[wv] = t;
        if (wv == 0) {
          while (ewflag[1] < t || ewflag[2] < t) {}
          MEMBAR;
          if (lane == 0) st_i32(fme, t + 2);
          MEMBAR;
          *ewdone = t;
        }
      }
    }
  } else {
    // ---- S3: per-step block barrier kept ----
    for (int t = 0; t < 1024; ++t) {
      if (w == 7) {
        poller(fS2, t+2, nullptr, 0, nullptr, 0, 0, ready, t, lane);
      } else if (w < 4) {
        const unsigned short* arow = h1 + (t & (NSLOT-1))*65536
                                     + (w*16 + (lane&15))*H + ((lane>>4)*8);
        s3_gemm(arow, frag + lane*8, ready, t, bo, out, base, lane, w);
      }
      WAITV(0);
      __syncthreads();
      if (tid == 0) st_i32(&fS3[p], t + 2);
    }
  }
}

extern "C" void kernel_launch(void* const* d_in, const int* in_sizes, int n_in,
                              void* d_out, int out_size, void* d_ws, size_t ws_size,
                              hipStream_t stream) {
  const float* z    = (const float*)d_in[0];
  // d_in[1] = seq_len (==1024, hard-coded); d_in[2] = W_ih_0 (unused: x0==0)
  const float* Whh0 = (const float*)d_in[3];
  const float* bih0 = (const float*)d_in[4];
  const float* bhh0 = (const float*)d_in[5];
  const float* Wih1 = (const float*)d_in[6];
  const float* Whh1 = (const float*)d_in[7];
  const float* bih1 = (const float*)d_in[8];
  const float* bhh1 = (const float*)d_in[9];
  const float* Wout = (const float*)d_in[10];
  const float* bout = (const float*)d_in[11];
  float* out = (float*)d_out;
  char* ws = (char*)d_ws;

  hipFuncSetAttribute((const void*)gru_pipeline,
                      hipFuncAttributeMaxDynamicSharedMemorySize, SMEM_BYTES);
  hipMemsetAsync(d_ws, 0, 4096, stream);   // flags

  void* args[] = { (void*)&z, (void*)&Whh0, (void*)&bih0, (void*)&bhh0,
                   (void*)&Wih1, (void*)&Whh1, (void*)&bih1, (void*)&bhh1,
                   (void*)&Wout, (void*)&bout, (void*)&out, (void*)&ws };
  hipLaunchCooperativeKernel((void*)gru_pipeline, dim3(NBLK), dim3(512),
                             args, SMEM_BYTES, stream);
}

// Round 7
// 9819.869 us; speedup vs baseline: 1.7455x; 1.2235x over previous
//
#include <hip/hip_runtime.h>

// DecoderGRU: 2-layer GRU (B=64, H=1024, T=1024, OUT=128) + output projection.
// R16 = R9 baseline + FLAG LINE PADDING (one 128B line per flag).
// R13/R14: step = ~5.5us data floor (per-CU bypass ingest cap, R15 proved
// CU-capped not wave-capped) + ~5.7us sync. R15: runahead/depth null.
// New theory: packed [4][64] int flags = 64 producer stores/step onto 4
// cache lines + ~192 poller lanes re-reading the same lines -> same-line
// serialization at the coherent point delays the LAST flag (ballot needs all
// 64) by ~us -> sits on the recurrence path every step. Fix: stride each
// flag to its own 128B line (32 KB total). Everything else = proven R9
// structure (2-deep gemm48, t-1 gates, 8-slot h rotation) + 8B h-stores.
//   S0 (blk 0-63):   h0^t = GRU0(h0^{t-1})        [16 units/blk]
//   S1 (blk 64-127): Gx^t = y0^t @ W_ih1^T        [16 units/blk]
//   S2 (blk 128-191): h1^t = GRU1(Gx^t, h1^{t-1}) [16 units/blk]
//   S3 (blk 192-199): out^t = y1^t @ W_out^T + b  [16 cols/blk]

#define NBLK 200
#define SMEM_BYTES 152576
#define H 1024
#define T 1024
#define NSLOT 8
#define SLOT(k) (((k) + NSLOT) & (NSLOT - 1))
#define FSTR 32                       // ints per flag (128-B line)
#define MEMBAR asm volatile("" ::: "memory")

typedef short s16x8 __attribute__((ext_vector_type(8)));
typedef float f32x4 __attribute__((ext_vector_type(4)));
typedef unsigned u32x2 __attribute__((ext_vector_type(2)));

__device__ __forceinline__ unsigned short f2bf(float f) {
  union { float f; unsigned u; } v; v.f = f;
  return (unsigned short)((v.u + 0x7FFFu + ((v.u >> 16) & 1u)) >> 16);
}
__device__ __forceinline__ float sigm(float x) { return 1.f / (1.f + __expf(-x)); }

__device__ __forceinline__ void st_u16(void* p, unsigned short v) {
  __hip_atomic_store((unsigned short*)p, v, __ATOMIC_RELAXED, __HIP_MEMORY_SCOPE_AGENT);
}
__device__ __forceinline__ void st_i32(int* p, int v) {
  __hip_atomic_store(p, v, __ATOMIC_RELAXED, __HIP_MEMORY_SCOPE_AGENT);
}
__device__ __forceinline__ int ld_i32(const int* p) {
  return __hip_atomic_load(p, __ATOMIC_RELAXED, __HIP_MEMORY_SCOPE_AGENT);
}

// ---- coalesced device-coherent loads/stores (bypass L1/L2) ---------------
#define GLD(d, p, off) \
  asm volatile("global_load_dwordx4 %0, %1, off offset:" #off " sc0 sc1" \
               : "=v"(d) : "v"(p))
#define GLDG(A, p) GLD(A[0],p,0); GLD(A[1],p,64); GLD(A[2],p,128); GLD(A[3],p,192)
#define WAITV(n) asm volatile("s_waitcnt vmcnt(" #n ")" ::: "memory")
#define TIE4(A) \
  asm volatile("" : "+v"(A[0]),"+v"(A[1]),"+v"(A[2]),"+v"(A[3]))

__device__ __forceinline__ void gst16f(f32x4 v, void* p) {
  asm volatile("global_store_dwordx4 %0, %1, off sc0 sc1" :: "v"(p), "v"(v) : "memory");
}
__device__ __forceinline__ void gst4(float v, void* p) {
  asm volatile("global_store_dword %0, %1, off sc0 sc1" :: "v"(p), "v"(v) : "memory");
}
__device__ __forceinline__ void gst8u(u32x2 v, void* p) {
  asm volatile("global_store_dwordx2 %0, %1, off sc0 sc1" :: "v"(p), "v"(v) : "memory");
}
__device__ __forceinline__ f32x4 gldf(const float* p) {
  f32x4 d;
  asm volatile("global_load_dwordx4 %0, %1, off sc0 sc1" : "=v"(d) : "v"(p));
  return d;
}

// Wave-7 poller, 2-deep pipelined; flags are line-strided (lane*FSTR).
__device__ __forceinline__ void poller(const int* fd, int dtgt,
                                       const int* fgx, int gtgt,
                                       const int* fa, int na, int atgt,
                                       volatile int* ready, int t, int lane) {
  {
    const int* fp = fd + lane * FSTR;
    int v = ld_i32(fp);
    for (;;) {
      int vn = ld_i32(fp);
      unsigned long long m = __ballot(v >= dtgt);
      if (lane < 8 && ((m >> (8 * lane)) & 0xFFull) == 0xFFull) ready[lane] = t;
      if (m == ~0ull) break;
      v = vn;
    }
  }
  if (fgx) {
    int v = (lane == 0) ? ld_i32(fgx) : 0x7fffffff;
    for (;;) {
      int vn = (lane == 0) ? ld_i32(fgx) : 0x7fffffff;
      if (__ballot(v < gtgt) == 0ull) break;
      v = vn;
    }
    if (lane == 0) ready[8] = t;
  }
  if (fa) {
    bool act = lane < na;
    const int* fp = fa + (act ? lane : 0) * FSTR;
    int v = act ? ld_i32(fp) : atgt;
    for (;;) {
      int vn = act ? ld_i32(fp) : atgt;
      if (__ballot(v < atgt) == 0ull) break;
      v = vn;
    }
  }
}

#define MF3(Ap, g) { \
  _Pragma("unroll") \
  for (int i = 0; i < 4; ++i) { int kb = (g)*4 + i; \
    s16x8 b0 = *(const s16x8*)(bb + (kb*3+0)*512); \
    s16x8 b1 = *(const s16x8*)(bb + (kb*3+1)*512); \
    s16x8 b2 = *(const s16x8*)(bb + (kb*3+2)*512); \
    a0 = __builtin_amdgcn_mfma_f32_16x16x32_bf16(Ap[i], b0, a0, 0, 0, 0); \
    a1 = __builtin_amdgcn_mfma_f32_16x16x32_bf16(Ap[i], b1, a1, 0, 0, 0); \
    a2 = __builtin_amdgcn_mfma_f32_16x16x32_bf16(Ap[i], b2, a2, 0, 0, 0); } }

#define MF1(Ap, g) { \
  _Pragma("unroll") \
  for (int i = 0; i < 4; ++i) { int kb = (g)*4 + i; \
    s16x8 b0 = *(const s16x8*)(bb + kb*512); \
    a0 = __builtin_amdgcn_mfma_f32_16x16x32_bf16(Ap[i], b0, a0, 0, 0, 0); } }

// N=48 GEMM, group-pipelined (R9's proven 2-deep structure).
__device__ __forceinline__ void gemm48(const unsigned short* arow,
                                       const unsigned short* bb,
                                       volatile int* ready, int t,
                                       float* G, int ldg, int lane, int w) {
  f32x4 a0 = {0,0,0,0}, a1 = {0,0,0,0}, a2 = {0,0,0,0};
  s16x8 A0[4], A1[4];
  while (ready[0] < t) {}
  MEMBAR;
  GLDG(A0, arow);
  while (ready[1] < t) {}
  MEMBAR;
  GLDG(A1, arow + 128);
  #pragma unroll
  for (int g2 = 1; g2 < 4; ++g2) {
    WAITV(4); TIE4(A0); MF3(A0, 2*g2 - 2);
    while (ready[2*g2] < t) {}
    MEMBAR;
    GLDG(A0, arow + g2*256);
    WAITV(4); TIE4(A1); MF3(A1, 2*g2 - 1);
    while (ready[2*g2 + 1] < t) {}
    MEMBAR;
    GLDG(A1, arow + g2*256 + 128);
  }
  WAITV(4); TIE4(A0); MF3(A0, 6);
  WAITV(0); TIE4(A1); MF3(A1, 7);
  int col = lane & 15, r0 = (lane >> 4) * 4;
  #pragma unroll
  for (int r = 0; r < 4; ++r) {
    int brow = w*16 + r0 + r;
    G[brow*ldg +      col] = a0[r];
    G[brow*ldg + 16 + col] = a1[r];
    G[brow*ldg + 32 + col] = a2[r];
  }
}

extern "C" __global__ void __launch_bounds__(512, 1)
gru_pipeline(const float* __restrict__ z,
             const float* __restrict__ Whh0,
             const float* __restrict__ bih0, const float* __restrict__ bhh0,
             const float* __restrict__ Wih1, const float* __restrict__ Whh1,
             const float* __restrict__ bih1, const float* __restrict__ bhh1,
             const float* __restrict__ Wout, const float* __restrict__ bout,
             float* __restrict__ out, char* __restrict__ ws)
{
  extern __shared__ char smem[];
  const int tid  = threadIdx.x;
  const int lane = tid & 63;
  const int w    = tid >> 6;
  const int bid  = blockIdx.x;

  int*            flags = (int*)ws;                         // [4][64] x FSTR ints
  unsigned short* h0    = (unsigned short*)(ws + 32768);    // 8 x 64x1024 bf16
  unsigned short* h1    = (unsigned short*)(ws + 1081344);  // 8 x 64x1024 bf16
  float*          gxw   = (float*)(ws + 2129920);           // 3 x 64x(64x48) f32

  int role, p;
  if (bid < 64)       { role = 0; p = bid; }
  else if (bid < 128) { role = 1; p = bid - 64; }
  else if (bid < 192) { role = 2; p = bid - 128; }
  else                { role = 3; p = bid - 192; }
  const int base = p * 16;

  unsigned short* frag = (unsigned short*)smem;
  float* G   = (float*)(smem + 98304);    // 2 x 64x49 f32 (double buffer)
  float* hm  = (float*)(smem + 123392);   // fp32 master state
  float* bi  = (float*)(smem + 127488);
  float* bh  = (float*)(smem + 127680);
  volatile int* ready  = (volatile int*)(smem + 127872);  // [9]
  volatile int* gdone  = (volatile int*)(smem + 127936);  // [4]
  volatile int* ewflag = (volatile int*)(smem + 127952);  // [3]
  volatile int* gxst   = (volatile int*)(smem + 127968);  // [3]
  volatile int* ewdone = (volatile int*)(smem + 127984);  // [1]
  float* gxl = (float*)(smem + 128000);   // S2: 2 x 64x48 f32 (double buffer)
  float* bo  = (float*)(smem + 32768);    // S3 only (past its 32KB frags)

  int* fS0 = flags;              int* fS1 = flags + 64*FSTR;
  int* fS2 = flags + 128*FSTR;   int* fS3 = flags + 192*FSTR;

  // ---------------- init: weights -> LDS bf16 B-fragments, prefill ----------
  if (tid < 9) ready[tid] = -1;
  if (tid == 0) {
    gdone[0] = gdone[1] = gdone[2] = gdone[3] = -1;
    ewflag[0] = ewflag[1] = ewflag[2] = -1;
    gxst[0] = gxst[1] = gxst[2] = -1;
    *ewdone = -1;
  }
  if (role < 3) {
    const float* W = (role == 0) ? Whh0 : (role == 1) ? Wih1 : Whh1;
    for (int q = tid; q < 6144; q += 512) {
      int c = q % 48; int r2 = q / 48; int grp = r2 & 3; int kb = r2 >> 2;
      int g = c >> 4, u = c & 15;
      unsigned short* dst = frag + (kb*3 + g)*512 + (grp*16 + u)*8;
      const float* s = W + (size_t)(g*H + base + u)*H + kb*32 + grp*8;
      #pragma unroll
      for (int j = 0; j < 8; ++j) dst[j] = f2bf(s[j]);
    }
  }
  if (role == 0 || role == 2) {
    const float* bip = (role == 0) ? bih0 : bih1;
    const float* bhp = (role == 0) ? bhh0 : bhh1;
    if (tid < 48) {
      int g = tid >> 4, u = tid & 15;
      bi[tid] = bip[g*H + base + u];
      bh[tid] = bhp[g*H + base + u];
    }
    unsigned short* hb = (role == 0) ? h0 : h1;
    for (int q = tid; q < 1024; q += 512) {
      int b = q >> 4, u = q & 15;
      float v = z[b*H + base + u];
      hm[q] = v;
      st_u16(&hb[(NSLOT-1)*65536 + b*H + base + u], f2bf(v));  // h^{-1} slot 7
    }
  } else if (role == 3) {
    for (int q = tid; q < 2048; q += 512) {
      int c = q & 15, grp = (q >> 4) & 3, kb = q >> 6;
      unsigned short* dst = frag + kb*512 + (grp*16 + c)*8;
      const float* s = Wout + (size_t)(base + c)*H + kb*32 + grp*8;
      #pragma unroll
      for (int j = 0; j < 8; ++j) dst[j] = f2bf(s[j]);
    }
    if (tid < 16) bo[tid] = bout[base + tid];
  }
  WAITV(0);
  __syncthreads();
  if (tid == 0) st_i32(&flags[(role*64 + p)*FSTR], 1);   // data-step -1 done

  // ---------------- barrier-free steady state (roles 0-2) ------------------
  if (role < 3) {
    unsigned short* hsrc = (role == 2) ? h1 : h0;   // GEMM A source
    if (w < 4) {
      // ---- GEMM waves: free-running, double-buffered G ----
      const int ldg = (role == 1) ? 48 : 49;
      const int dt  = (role == 1) ? 0 : 1;          // A slot: t-dt
      for (int t = 0; t < 1024; ++t) {
        while (*ewdone < t - 2) {}
        MEMBAR;
        const unsigned short* arow = hsrc + SLOT(t - dt)*65536
                                     + (w*16 + (lane&15))*H + ((lane>>4)*8);
        gemm48(arow, frag + lane*8, ready, t, G + (t&1)*3136, ldg, lane, w);
        MEMBAR;
        gdone[w] = t;
      }
    } else if (w == 7) {
      // ---- poller wave (R9 targets; line-strided flags) ----
      for (int t = 0; t < 1024; ++t) {
        if (role == 0)      poller(fS0, t+1, nullptr, 0, fS1, 64, t-1, ready, t, lane);
        else if (role == 1) poller(fS0, t+2, nullptr, 0, fS2, 64, t-1, ready, t, lane);
        else                poller(fS2, t+1, &fS1[p*FSTR], t+2, fS3, 8, t-1, ready, t, lane);
      }
    } else {
      // ---- ew waves 4-6 ----
      const int wv = w - 4;
      const int ewt = wv*64 + lane;                 // 0..191
      int* fme = flags + (role*64 + p)*FSTR;
      for (int t = 0; t < 1024; ++t) {
        if (role == 2) {
          // stage gx^t -> gxl[t&1] (coalesced, off the GEMM waves)
          while (ready[8] < t) {}
          MEMBAR;
          const float* gxp = gxw + (size_t)(t % 3)*196608 + p*3072
                             + wv*1024 + lane*16;
          f32x4 ga = gldf(gxp), gb = gldf(gxp + 4),
                gc = gldf(gxp + 8), gd = gldf(gxp + 12);
          WAITV(0);
          asm volatile("" : "+v"(ga), "+v"(gb), "+v"(gc), "+v"(gd));
          float* dstl = gxl + (t&1)*3072 + wv*1024 + lane*16;
          *(f32x4*)(dstl)      = ga; *(f32x4*)(dstl + 4)  = gb;
          *(f32x4*)(dstl + 8)  = gc; *(f32x4*)(dstl + 12) = gd;
          MEMBAR;
          gxst[wv] = t;
          while (gxst[0] < t || gxst[1] < t || gxst[2] < t) {}
          MEMBAR;
        }
        while (gdone[0] < t || gdone[1] < t || gdone[2] < t || gdone[3] < t) {}
        MEMBAR;
        float* Gt = G + (t&1)*3136;
        if (role == 1) {
          // dump Gx to global
          float* dst = gxw + (size_t)(t % 3)*196608 + p*3072;
          for (int c2 = ewt; c2 < 768; c2 += 192)
            gst16f(*(f32x4*)(Gt + c2*4), dst + c2*4);
        } else {
          float* gx2 = gxl + (t&1)*3072;
          unsigned short* hdst = hsrc + SLOT(t)*65536;
          for (int q = ewt; q < 256; q += 192) {
            int b = q >> 2, u0 = (q & 3) * 4;
            unsigned pk2[2];
            #pragma unroll
            for (int jj = 0; jj < 2; ++jj) {
              unsigned short pk[2];
              #pragma unroll
              for (int j = 0; j < 2; ++j) {
                int u = u0 + jj*2 + j;
                float xr, xz, xn;
                if (role == 0) {                 // gx = b_ih_0 (x == 0)
                  xr = bi[u]; xz = bi[16 + u]; xn = bi[32 + u];
                } else {
                  xr = gx2[b*48 + u]      + bi[u];
                  xz = gx2[b*48 + 16 + u] + bi[16 + u];
                  xn = gx2[b*48 + 32 + u] + bi[32 + u];
                }
                float hr = Gt[b*49 + u]      + bh[u];
                float hz = Gt[b*49 + 16 + u] + bh[16 + u];
                float hn = Gt[b*49 + 32 + u] + bh[32 + u];
                float r  = sigm(xr + hr);
                float zg = sigm(xz + hz);
                float n  = tanhf(xn + r * hn);
                int idx = b*16 + u;
                float hp = hm[idx];
                float hv = (1.f - zg) * n + zg * hp;
                hm[idx] = hv;
                pk[j] = f2bf(hv);
              }
              pk2[jj] = (unsigned)pk[0] | ((unsigned)pk[1] << 16);
            }
            u32x2 v2; v2.x = pk2[0]; v2.y = pk2[1];
            gst8u(v2, &hdst[b*H + base + u0]);
          }
        }
        WAITV(0);
        MEMBAR;
        ewflag[wv] = t;
        if (wv == 0) {
          while (ewflag[1] < t || ewflag[2] < t) {}
          MEMBAR;
          if (lane == 0) st_i32(fme, t + 2);
          MEMBAR;
          *ewdone = t;
        }
      }
    }
  } else {
    // ---- S3: per-step block barrier kept ----
    for (int t = 0; t < 1024; ++t) {
      if (w == 7) {
        poller(fS2, t+2, nullptr, 0, nullptr, 0, 0, ready, t, lane);
      } else if (w < 4) {
        const unsigned short* arow = h1 + (t & (NSLOT-1))*65536
                                     + (w*16 + (lane&15))*H + ((lane>>4)*8);
        const unsigned short* bb = frag + lane*8;
        f32x4 a0 = {0,0,0,0};
        s16x8 A0[4], A1[4];
        while (ready[0] < t) {}
        MEMBAR;
        GLDG(A0, arow);
        while (ready[1] < t) {}
        MEMBAR;
        GLDG(A1, arow + 128);
        #pragma unroll
        for (int g2i = 1; g2i < 4; ++g2i) {
          WAITV(4); TIE4(A0); MF1(A0, 2*g2i - 2);
          while (ready[2*g2i] < t) {}
          MEMBAR;
          GLDG(A0, arow + g2i*256);
          WAITV(4); TIE4(A1); MF1(A1, 2*g2i - 1);
          while (ready[2*g2i + 1] < t) {}
          MEMBAR;
          GLDG(A1, arow + g2i*256 + 128);
        }
        WAITV(4); TIE4(A0); MF1(A0, 6);
        WAITV(0); TIE4(A1); MF1(A1, 7);
        int col = lane & 15, r0 = (lane >> 4) * 4;
        #pragma unroll
        for (int r = 0; r < 4; ++r) {
          int brow = w*16 + r0 + r;
          gst4(a0[r] + bo[col], out + (size_t)(brow*T + t)*128 + base + col);
        }
      }
      WAITV(0);
      __syncthreads();
      if (tid == 0) st_i32(&fS3[p*FSTR], t + 2);
    }
  }
}

extern "C" void kernel_launch(void* const* d_in, const int* in_sizes, int n_in,
                              void* d_out, int out_size, void* d_ws, size_t ws_size,
                              hipStream_t stream) {
  const float* z    = (const float*)d_in[0];
  // d_in[1] = seq_len (==1024, hard-coded); d_in[2] = W_ih_0 (unused: x0==0)
  const float* Whh0 = (const float*)d_in[3];
  const float* bih0 = (const float*)d_in[4];
  const float* bhh0 = (const float*)d_in[5];
  const float* Wih1 = (const float*)d_in[6];
  const float* Whh1 = (const float*)d_in[7];
  const float* bih1 = (const float*)d_in[8];
  const float* bhh1 = (const float*)d_in[9];
  const float* Wout = (const float*)d_in[10];
  const float* bout = (const float*)d_in[11];
  float* out = (float*)d_out;
  char* ws = (char*)d_ws;

  hipFuncSetAttribute((const void*)gru_pipeline,
                      hipFuncAttributeMaxDynamicSharedMemorySize, SMEM_BYTES);
  hipMemsetAsync(d_ws, 0, 32768, stream);   // line-strided flags

  void* args[] = { (void*)&z, (void*)&Whh0, (void*)&bih0, (void*)&bhh0,
                   (void*)&Wih1, (void*)&Whh1, (void*)&bih1, (void*)&bhh1,
                   (void*)&Wout, (void*)&bout, (void*)&out, (void*)&ws };
  hipLaunchCooperativeKernel((void*)gru_pipeline, dim3(NBLK), dim3(512),
                             args, SMEM_BYTES, stream);
}